// Round 1
// baseline (197.530 us; speedup 1.0000x reference)
//
#include <hip/hip_runtime.h>

#define ALPHA 0.2f

constexpr int BB  = 4;
constexpr int NN  = 2048;
constexpr int FIN = 128;
constexpr int FO  = 64;
constexpr int HH  = 4;
constexpr int CC  = BB * HH;   // 16 (b,h) combos

using half8  = __attribute__((ext_vector_type(8))) _Float16;
using floatx4 = __attribute__((ext_vector_type(4))) float;

// ---------------------------------------------------------------------------
// K1: projection ht[c][f][n] (f16, transposed for PV B-operand) + e_src/e_dst
// grid: B * (N/32) = 256 blocks, 256 threads. Each block: 32 nodes, all (h,f).
// ---------------------------------------------------------------------------
__global__ __launch_bounds__(256) void gat_k1_prep(
    const float* __restrict__ h, const float* __restrict__ W,
    const float* __restrict__ a, _Float16* __restrict__ htT,
    float* __restrict__ esrc, float* __restrict__ edst) {
  const int blk = blockIdx.x;
  const int b = blk >> 6;          // /64 tiles per batch
  const int n0 = (blk & 63) * 32;
  const int t = threadIdx.x;
  const int hh = t >> 6;           // head == wave index
  const int f  = t & 63;           // lane == output feature

  __shared__ __align__(16) float X[32 * FIN];  // 16 KB node tile
  {
    const float4* src = (const float4*)(h + (size_t)(b * NN + n0) * FIN);
    float4* dst = (float4*)X;
#pragma unroll
    for (int r = 0; r < 4; ++r) dst[r * 256 + t] = src[r * 256 + t];
  }
  __syncthreads();

  float acc[32];
#pragma unroll
  for (int nd = 0; nd < 32; ++nd) acc[nd] = 0.f;

  const float* Wp = W + (size_t)hh * FIN * FO + f;   // W[h][i][f], stride 64 over i
  for (int i4 = 0; i4 < FIN / 4; ++i4) {
    const float w0 = Wp[(i4 * 4 + 0) * FO];
    const float w1 = Wp[(i4 * 4 + 1) * FO];
    const float w2 = Wp[(i4 * 4 + 2) * FO];
    const float w3 = Wp[(i4 * 4 + 3) * FO];
#pragma unroll
    for (int nd = 0; nd < 32; ++nd) {
      // broadcast LDS read (uniform address across wave) — conflict-free
      const float4 x = *(const float4*)&X[nd * FIN + i4 * 4];
      acc[nd] = fmaf(x.x, w0, fmaf(x.y, w1, fmaf(x.z, w2, fmaf(x.w, w3, acc[nd]))));
    }
  }

  // e_src / e_dst: wave (=head) reduction over f lanes
  const float asv = a[hh * 128 + f];
  const float adv = a[hh * 128 + 64 + f];
  const int c = b * HH + hh;
#pragma unroll
  for (int nd = 0; nd < 32; ++nd) {
    float vs = acc[nd] * asv;
    float vd = acc[nd] * adv;
#pragma unroll
    for (int off = 32; off > 0; off >>= 1) {
      vs += __shfl_xor(vs, off, 64);
      vd += __shfl_xor(vd, off, 64);
    }
    if (f == 0) {
      esrc[c * NN + n0 + nd] = vs;
      edst[c * NN + n0 + nd] = vd;
    }
  }

  // write htT[c][f][n0..n0+32) as f16 (64B contiguous per thread)
  _Float16* outp = htT + ((size_t)(c * FO + f) * NN + n0);
#pragma unroll
  for (int k = 0; k < 4; ++k) {
    half8 v;
#pragma unroll
    for (int j = 0; j < 8; ++j) v[j] = (_Float16)acc[k * 8 + j];
    *(half8*)(outp + k * 8) = v;
  }
}

// ---------------------------------------------------------------------------
// K2: per-row softmax stats (max, 1/sum) for all 16 (b,h) + adjacency bitpack.
// grid: N/4 = 512 blocks, 256 threads; one wave per adjacency row m.
// adj is read from HBM exactly once (16 MB total).
// ---------------------------------------------------------------------------
__global__ __launch_bounds__(256) void gat_k2_stats(
    const float* __restrict__ adj, const float* __restrict__ esrc,
    const float* __restrict__ edst, unsigned* __restrict__ adjbits,
    float* __restrict__ rmax, float* __restrict__ rsuminv) {
  const int t = threadIdx.x;
  const int w = t >> 6, l = t & 63;
  const int m = blockIdx.x * 4 + w;

  float areg[32];
  const float* arow = adj + (size_t)m * NN;
#pragma unroll
  for (int j = 0; j < 32; ++j) areg[j] = arow[j * 64 + l];

  // bit-pack: bit i of word (m, n>>5) = adj[m][n] != 0
#pragma unroll
  for (int j = 0; j < 32; ++j) {
    const unsigned long long mask = __ballot(areg[j] != 0.f);
    if (l == 0) {
      adjbits[m * 64 + j * 2 + 0] = (unsigned)mask;
      adjbits[m * 64 + j * 2 + 1] = (unsigned)(mask >> 32);
    }
  }

  for (int c = 0; c < CC; ++c) {
    const float em = esrc[c * NN + m];
    float svals[32];
    float mx = -3.4e38f;
#pragma unroll
    for (int j = 0; j < 32; ++j) {
      const float ed = edst[c * NN + j * 64 + l];
      float s = em + ed;
      s = (s >= 0.f) ? s : ALPHA * s;
      // matches ref: lrelu(e) + (-1e20) rounds to -1e20 exactly in fp32
      s = (areg[j] != 0.f) ? s : s - 1e20f;
      svals[j] = s;
      mx = fmaxf(mx, s);
    }
#pragma unroll
    for (int off = 32; off > 0; off >>= 1) mx = fmaxf(mx, __shfl_xor(mx, off, 64));
    float sm = 0.f;
#pragma unroll
    for (int j = 0; j < 32; ++j) sm += __expf(svals[j] - mx);
#pragma unroll
    for (int off = 32; off > 0; off >>= 1) sm += __shfl_xor(sm, off, 64);
    if (l == 0) {
      rmax[c * NN + m] = mx;
      rsuminv[c * NN + m] = 1.f / sm;
    }
  }
}

// ---------------------------------------------------------------------------
// K3: O[m][f] = sum_n P[m][n] * V[n][f] with P computed on the fly (f16 MFMA).
// grid: 16 (b,h) * 32 m-tiles = 512 blocks, 256 threads (4 waves).
// Block tile: 64 rows x 64 f. Wave w owns rows [w*16, w*16+16).
// ---------------------------------------------------------------------------
__global__ __launch_bounds__(256) void gat_k3_pv(
    const _Float16* __restrict__ htT, const float* __restrict__ esrc,
    const float* __restrict__ edst, const unsigned* __restrict__ adjbits,
    const float* __restrict__ rmax, const float* __restrict__ rsuminv,
    float* __restrict__ out) {
  const int blk = blockIdx.x;
  const int c = blk >> 5;
  const int mt = blk & 31;
  const int m0 = mt * 64;
  const int b = c >> 2, hh = c & 3;
  const int t = threadIdx.x;
  const int w = t >> 6, lane = t & 63;
  const int q = lane >> 4, r16 = lane & 15;

  __shared__ __align__(16) _Float16 P[64][72];   // +8 pad: bank spread for A reads
  __shared__ __align__(16) _Float16 Vt[64][72];  // Vt[f][n_local]

  // P-compute assignment: thread -> (row pm, 16-col segment ns)
  const int pm = t >> 2;
  const int ns = t & 3;
  const float em = esrc[c * NN + m0 + pm];
  const float rm = rmax[c * NN + m0 + pm];
  const float ri = rsuminv[c * NN + m0 + pm];
  const float* edc = edst + c * NN;
  const unsigned* abrow = adjbits + (size_t)(m0 + pm) * 64;
  const uint4* htbase = (const uint4*)(htT + (size_t)c * FO * NN);

  floatx4 acc[4];
#pragma unroll
  for (int ft = 0; ft < 4; ++ft) acc[ft] = floatx4{0.f, 0.f, 0.f, 0.f};

  for (int n0 = 0; n0 < NN; n0 += 64) {
    __syncthreads();
    // stage V tile: htT already [f][n] — plain row-major copy, no transpose
#pragma unroll
    for (int it = 0; it < 2; ++it) {
      const int idx = t + it * 256;
      const int fr = idx >> 3, sg = idx & 7;
      const uint4 v = htbase[((size_t)fr * NN + n0) / 8 + sg];
      *(uint4*)&Vt[fr][sg * 8] = v;
    }
    // compute P tile (rsuminv folded in)
    {
      const unsigned word = abrow[(n0 >> 5) + (ns >> 1)];
      const unsigned bits = (word >> ((ns & 1) * 16)) & 0xFFFFu;
      const float4* edp = (const float4*)(edc + n0 + ns * 16);
      const float4 ea = edp[0], eb = edp[1], ec = edp[2], ee = edp[3];
      const float edarr[16] = {ea.x, ea.y, ea.z, ea.w, eb.x, eb.y, eb.z, eb.w,
                               ec.x, ec.y, ec.z, ec.w, ee.x, ee.y, ee.z, ee.w};
      half8 pv0, pv1;
#pragma unroll
      for (int k = 0; k < 8; ++k) {
        float s = em + edarr[k];
        s = (s >= 0.f) ? s : ALPHA * s;
        s = ((bits >> k) & 1u) ? s : s - 1e20f;
        pv0[k] = (_Float16)(__expf(s - rm) * ri);
      }
#pragma unroll
      for (int k = 0; k < 8; ++k) {
        float s = em + edarr[8 + k];
        s = (s >= 0.f) ? s : ALPHA * s;
        s = ((bits >> (8 + k)) & 1u) ? s : s - 1e20f;
        pv1[k] = (_Float16)(__expf(s - rm) * ri);
      }
      *(half8*)&P[pm][ns * 16 + 0] = pv0;
      *(half8*)&P[pm][ns * 16 + 8] = pv1;
    }
    __syncthreads();
    // MFMA: A = P rows (m), B = Vt rows (f), K = 64 per tile
#pragma unroll
    for (int kk = 0; kk < 64; kk += 32) {
      const half8 afrag = *(const half8*)&P[w * 16 + r16][kk + q * 8];
#pragma unroll
      for (int ft = 0; ft < 4; ++ft) {
        const half8 bfrag = *(const half8*)&Vt[ft * 16 + r16][kk + q * 8];
        acc[ft] = __builtin_amdgcn_mfma_f32_16x16x32_f16(afrag, bfrag, acc[ft], 0, 0, 0);
      }
    }
  }

  // epilogue: C/D layout col = lane&15, row = quad*4 + reg
#pragma unroll
  for (int ft = 0; ft < 4; ++ft) {
#pragma unroll
    for (int r = 0; r < 4; ++r) {
      const int mrow = m0 + w * 16 + q * 4 + r;
      const int fcol = ft * 16 + r16;
      out[((size_t)(b * NN + mrow)) * 256 + hh * 64 + fcol] = acc[ft][r];
    }
  }
}

// ---------------------------------------------------------------------------
extern "C" void kernel_launch(void* const* d_in, const int* in_sizes, int n_in,
                              void* d_out, int out_size, void* d_ws, size_t ws_size,
                              hipStream_t stream) {
  const float* h   = (const float*)d_in[0];   // (4,2048,128)
  const float* adj = (const float*)d_in[1];   // (2048,2048)
  const float* W   = (const float*)d_in[2];   // (4,128,64)
  const float* a   = (const float*)d_in[3];   // (4,128,1)
  float* out = (float*)d_out;                  // (4,2048,256)

  char* ws = (char*)d_ws;
  _Float16* htT   = (_Float16*)(ws);                        // 16*64*2048*2 = 4 MB
  float* esrc     = (float*)(ws + 4 * 1024 * 1024);          // 128 KB
  float* edst     = (float*)(ws + 4 * 1024 * 1024 + 131072); // 128 KB
  unsigned* abits = (unsigned*)(ws + 4 * 1024 * 1024 + 2 * 131072);            // 512 KB
  float* rmax     = (float*)(ws + 4 * 1024 * 1024 + 2 * 131072 + 524288);      // 128 KB
  float* rsuminv  = (float*)(ws + 4 * 1024 * 1024 + 2 * 131072 + 524288 + 131072);

  gat_k1_prep<<<dim3(BB * (NN / 32)), dim3(256), 0, stream>>>(h, W, a, htT, esrc, edst);
  gat_k2_stats<<<dim3(NN / 4), dim3(256), 0, stream>>>(adj, esrc, edst, abits, rmax, rsuminv);
  gat_k3_pv<<<dim3(CC * (NN / 64)), dim3(256), 0, stream>>>(htT, esrc, edst, abits, rmax,
                                                            rsuminv, out);
}

// Round 3
// 146.232 us; speedup vs baseline: 1.3508x; 1.3508x over previous
//
#include <hip/hip_runtime.h>

#define ALPHA 0.2f

constexpr int BB  = 4;
constexpr int NN  = 2048;
constexpr int FIN = 128;
constexpr int FO  = 64;
constexpr int HH  = 4;
constexpr int CC  = BB * HH;   // 16 (b,h) combos

using half8   = __attribute__((ext_vector_type(8))) _Float16;
using floatx4 = __attribute__((ext_vector_type(4))) float;

__device__ __forceinline__ void fma4(float4& A, float xs, const float4& Wv) {
  A.x = fmaf(xs, Wv.x, A.x);
  A.y = fmaf(xs, Wv.y, A.y);
  A.z = fmaf(xs, Wv.z, A.z);
  A.w = fmaf(xs, Wv.w, A.w);
}

// ---------------------------------------------------------------------------
// K1: projection ht = h·W  (fp32 vector FMA, register-blocked 8n x 4o per
// thread), esrc/edst fused, htT written f16 transposed [c][f][n] via LDS
// transpose. grid 256 blocks x 256 thr; wave = head.
// ---------------------------------------------------------------------------
__global__ __launch_bounds__(256) void gat_k1_prep(
    const float* __restrict__ h, const float* __restrict__ W,
    const float* __restrict__ a, _Float16* __restrict__ htT,
    float* __restrict__ esrc, float* __restrict__ edst) {
  const int blk = blockIdx.x;
  const int b = blk >> 6;
  const int n0 = (blk & 63) * 32;
  const int t = threadIdx.x;
  const int hh = t >> 6;         // head = wave
  const int lane = t & 63;
  const int ng = lane >> 4;      // nodes ng + 4j  (stride-4: bank spread)
  const int og = lane & 15;      // out cols og*4 .. +4

  __shared__ __align__(16) float X[32 * 136];   // 17408 B, stride 136 floats
  __shared__ __align__(16) char  WBuf[32768];   // W k-chunk / htl transpose
  float* Wc = (float*)WBuf;
  _Float16* htl = (_Float16*)WBuf;

  // stage X[32][128] (row stride 136)
  {
    const float4* src = (const float4*)(h + (size_t)(b * NN + n0) * FIN);
#pragma unroll
    for (int i = 0; i < 4; ++i) {
      const int idx = t + i * 256;
      const int row = idx >> 5, c4 = idx & 31;
      *(float4*)&X[row * 136 + c4 * 4] = src[row * 32 + c4];
    }
  }

  float4 acc[8];
#pragma unroll
  for (int j = 0; j < 8; ++j) acc[j] = float4{0.f, 0.f, 0.f, 0.f};

  for (int kc = 0; kc < 4; ++kc) {
    __syncthreads();
    {  // stage Wc = W[:, kc*32:(kc+1)*32, :]  as [4][32][64] f32
      const float4* Wg = (const float4*)W;
      float4* Wc4 = (float4*)Wc;
#pragma unroll
      for (int r = 0; r < 8; ++r) {
        const int idx = t + r * 256;            // 0..2047 float4s
        const int wh = idx >> 9, rest = idx & 511;
        Wc4[idx] = Wg[wh * 2048 + kc * 512 + rest];
      }
    }
    __syncthreads();
    const float4* Wc4 = (const float4*)Wc;
#pragma unroll
    for (int k4 = 0; k4 < 8; ++k4) {
      const float4 w0 = Wc4[hh * 512 + (k4 * 4 + 0) * 16 + og];
      const float4 w1 = Wc4[hh * 512 + (k4 * 4 + 1) * 16 + og];
      const float4 w2 = Wc4[hh * 512 + (k4 * 4 + 2) * 16 + og];
      const float4 w3 = Wc4[hh * 512 + (k4 * 4 + 3) * 16 + og];
#pragma unroll
      for (int j = 0; j < 8; ++j) {
        const float4 x = *(const float4*)&X[(ng + 4 * j) * 136 + kc * 32 + k4 * 4];
        fma4(acc[j], x.x, w0);
        fma4(acc[j], x.y, w1);
        fma4(acc[j], x.z, w2);
        fma4(acc[j], x.w, w3);
      }
    }
  }

  // esrc/edst: partial dot over this thread's 4 cols, reduce over 16 og lanes
  const float4 as4 = *(const float4*)&a[hh * 128 + og * 4];
  const float4 ad4 = *(const float4*)&a[hh * 128 + 64 + og * 4];
  const int c = b * HH + hh;
#pragma unroll
  for (int j = 0; j < 8; ++j) {
    float es = acc[j].x * as4.x + acc[j].y * as4.y + acc[j].z * as4.z + acc[j].w * as4.w;
    float ed = acc[j].x * ad4.x + acc[j].y * ad4.y + acc[j].z * ad4.z + acc[j].w * ad4.w;
#pragma unroll
    for (int off = 1; off < 16; off <<= 1) {
      es += __shfl_xor(es, off, 64);
      ed += __shfl_xor(ed, off, 64);
    }
    if (og == 0) {
      esrc[c * NN + n0 + ng + 4 * j] = es;
      edst[c * NN + n0 + ng + 4 * j] = ed;
    }
  }

  __syncthreads();   // Wc reads done; reuse WBuf as htl [4][64][40] f16
#pragma unroll
  for (int j = 0; j < 8; ++j) {
    const int n = ng + 4 * j;
    htl[(hh * 64 + og * 4 + 0) * 40 + n] = (_Float16)acc[j].x;
    htl[(hh * 64 + og * 4 + 1) * 40 + n] = (_Float16)acc[j].y;
    htl[(hh * 64 + og * 4 + 2) * 40 + n] = (_Float16)acc[j].z;
    htl[(hh * 64 + og * 4 + 3) * 40 + n] = (_Float16)acc[j].w;
  }
  __syncthreads();
  {  // coalesced-ish writeout: thread t owns (head t>>6, f t&63), 32 n (64 B)
    const int h2 = t >> 6, f2 = t & 63;
    const uint4* srcl = (const uint4*)&htl[(h2 * 64 + f2) * 40];
    uint4* dst = (uint4*)(htT + (((size_t)(b * HH + h2) * 64 + f2) * NN + n0));
#pragma unroll
    for (int r = 0; r < 4; ++r) dst[r] = srcl[r];
  }
}

// ---------------------------------------------------------------------------
// K2: adjacency bitpack + rmax[c][m] = lrelu(esrc + masked-max(edst)).
// NO exp (lrelu monotone => max commutes). grid 512 x 256; wave per row.
// ---------------------------------------------------------------------------
__global__ __launch_bounds__(256) void gat_k2_stats(
    const float* __restrict__ adj, const float* __restrict__ esrc,
    const float* __restrict__ edst, unsigned* __restrict__ adjbits,
    float* __restrict__ rmax) {
  const int t = threadIdx.x;
  const int w = t >> 6, l = t & 63;
  const int m = blockIdx.x * 4 + w;

  float areg[32];
  const float* arow = adj + (size_t)m * NN;
#pragma unroll
  for (int j = 0; j < 32; ++j) areg[j] = arow[j * 64 + l];

#pragma unroll
  for (int j = 0; j < 32; ++j) {
    const unsigned long long mask = __ballot(areg[j] != 0.f);
    if (l == 0) {
      adjbits[m * 64 + j * 2 + 0] = (unsigned)mask;
      adjbits[m * 64 + j * 2 + 1] = (unsigned)(mask >> 32);
    }
  }

  for (int cc = 0; cc < CC; ++cc) {
    float mx = -3.0e38f;
#pragma unroll
    for (int j = 0; j < 32; ++j) {
      float ed = edst[cc * NN + j * 64 + l];
      ed = (areg[j] != 0.f) ? ed : -3.0e38f;
      mx = fmaxf(mx, ed);
    }
#pragma unroll
    for (int off = 32; off > 0; off >>= 1) mx = fmaxf(mx, __shfl_xor(mx, off, 64));
    if (l == 0) {
      const float s = esrc[cc * NN + m] + mx;
      rmax[cc * NN + m] = (s >= 0.f) ? s : ALPHA * s;
    }
  }
}

// ---------------------------------------------------------------------------
// K3: O = softmax(P)·V, P built on the fly DIRECTLY in A-fragment registers
// (no LDS P). V double-buffered via async global_load_lds with XOR swizzle.
// Unnormalized accumulate + psum; epilogue divides. grid 512 x 256.
// ---------------------------------------------------------------------------
__global__ __launch_bounds__(256) void gat_k3_pv(
    const _Float16* __restrict__ htT, const float* __restrict__ esrc,
    const float* __restrict__ edst, const unsigned* __restrict__ adjbits,
    const float* __restrict__ rmax, float* __restrict__ out) {
  const int blk = blockIdx.x;
  const int c = blk >> 5;
  const int m0 = (blk & 31) * 64;
  const int b = c >> 2, hh = c & 3;
  const int t = threadIdx.x;
  const int w = t >> 6, lane = t & 63;
  const int q = lane >> 4, r16 = lane & 15;
  const int row = m0 + w * 16 + r16;   // this thread's A-fragment row

  __shared__ __align__(16) _Float16 Vt[2 * 64 * 64];  // 2 x 8 KB, swizzled
  __shared__ float rowsum[64];

  const float em = esrc[c * NN + row];
  const float rm = rmax[c * NN + row];
  const float* edc = edst + (size_t)c * NN;
  const unsigned* abrow = adjbits + (size_t)row * 64;
  const _Float16* vsrc = htT + (size_t)c * FO * NN;

  // stage thread->chunk mapping: chunk idx = t (and t+256); row fr, slot sg.
  // XOR swizzle: LDS slot sg of row fr holds global chunk sg^(fr&7).
  const int fr0 = t >> 3, sg0 = t & 7;
  const int fr1 = (t + 256) >> 3;
  const size_t goff0 = (size_t)fr0 * NN + (size_t)((sg0 ^ (fr0 & 7)) * 8);
  const size_t goff1 = (size_t)fr1 * NN + (size_t)((sg0 ^ (fr1 & 7)) * 8);

  floatx4 acc[4];
#pragma unroll
  for (int ft = 0; ft < 4; ++ft) acc[ft] = floatx4{0.f, 0.f, 0.f, 0.f};
  float psum = 0.f;

#define STAGE(BUF, NBASE)                                                      \
  do {                                                                         \
    __builtin_amdgcn_global_load_lds(                                          \
        (const __attribute__((address_space(1))) void*)(vsrc + goff0 + (NBASE)),\
        (__attribute__((address_space(3))) void*)((char*)Vt + (BUF)*8192 + t*16),\
        16, 0, 0);                                                             \
    __builtin_amdgcn_global_load_lds(                                          \
        (const __attribute__((address_space(1))) void*)(vsrc + goff1 + (NBASE)),\
        (__attribute__((address_space(3))) void*)((char*)Vt + (BUF)*8192 + (t+256)*16),\
        16, 0, 0);                                                             \
  } while (0)

  STAGE(0, 0);

  for (int it = 0; it < 32; ++it) {
    const int n0 = it * 64;
    // ---- build A-fragments (this row, k = q*8..+8 within each 32-window)
    half8 afrag[2];
    const uint2 bw = *(const uint2*)&abrow[n0 >> 5];
    const float4* edp = (const float4*)(edc + n0);
#pragma unroll
    for (int kk2 = 0; kk2 < 2; ++kk2) {
      const float4 ea = edp[kk2 * 8 + q * 2];
      const float4 eb = edp[kk2 * 8 + q * 2 + 1];
      const float xs[8] = {ea.x, ea.y, ea.z, ea.w, eb.x, eb.y, eb.z, eb.w};
      const unsigned bits = ((kk2 == 0) ? bw.x : bw.y) >> (q * 8);
#pragma unroll
      for (int k = 0; k < 8; ++k) {
        float s = em + xs[k];
        s = (s >= 0.f) ? s : ALPHA * s;
        float p = __expf(s - rm);
        p = ((bits >> k) & 1u) ? p : 0.f;
        psum += p;
        afrag[kk2][k] = (_Float16)p;
      }
    }
    // barrier (drains vmcnt: current buffer's DMA complete everywhere)
    __syncthreads();
    if (it + 1 < 32) STAGE((it + 1) & 1, n0 + 64);
    // ---- MFMA from swizzled LDS V tile
    const int bufo = (it & 1) * 4096;  // halves
#pragma unroll
    for (int kk2 = 0; kk2 < 2; ++kk2) {
#pragma unroll
      for (int ft = 0; ft < 4; ++ft) {
        const int fr = ft * 16 + r16;
        const int cq = kk2 * 4 + q;
        const half8 bfrag =
            *(const half8*)&Vt[bufo + fr * 64 + ((cq ^ (fr & 7)) * 8)];
        acc[ft] = __builtin_amdgcn_mfma_f32_16x16x32_f16(afrag[kk2], bfrag,
                                                         acc[ft], 0, 0, 0);
      }
    }
  }

  // ---- row sums: reduce over the 4 q-lanes sharing this row
  psum += __shfl_xor(psum, 16, 64);
  psum += __shfl_xor(psum, 32, 64);
  if (q == 0) rowsum[w * 16 + r16] = psum;
  __syncthreads();

  // ---- epilogue: C layout col=lane&15, row=q*4+reg; normalize
#pragma unroll
  for (int x = 0; x < 4; ++x) {
    const float rinv = 1.0f / rowsum[w * 16 + q * 4 + x];
    const int mrow = m0 + w * 16 + q * 4 + x;
    float* op = out + ((size_t)b * NN + mrow) * 256 + hh * 64;
#pragma unroll
    for (int ft = 0; ft < 4; ++ft) op[ft * 16 + r16] = acc[ft][x] * rinv;
  }
#undef STAGE
}

// ---------------------------------------------------------------------------
extern "C" void kernel_launch(void* const* d_in, const int* in_sizes, int n_in,
                              void* d_out, int out_size, void* d_ws, size_t ws_size,
                              hipStream_t stream) {
  const float* h   = (const float*)d_in[0];   // (4,2048,128)
  const float* adj = (const float*)d_in[1];   // (2048,2048)
  const float* W   = (const float*)d_in[2];   // (4,128,64)
  const float* a   = (const float*)d_in[3];   // (4,128,1)
  float* out = (float*)d_out;                  // (4,2048,256)

  char* ws = (char*)d_ws;
  _Float16* htT   = (_Float16*)(ws);                         // 4 MB
  float* esrc     = (float*)(ws + 4 * 1024 * 1024);           // 128 KB
  float* edst     = (float*)(ws + 4 * 1024 * 1024 + 131072);  // 128 KB
  unsigned* abits = (unsigned*)(ws + 4 * 1024 * 1024 + 2 * 131072);        // 512 KB
  float* rmax     = (float*)(ws + 4 * 1024 * 1024 + 2 * 131072 + 524288);  // 128 KB

  gat_k1_prep<<<dim3(BB * (NN / 32)), dim3(256), 0, stream>>>(h, W, a, htT, esrc, edst);
  gat_k2_stats<<<dim3(NN / 4), dim3(256), 0, stream>>>(adj, esrc, edst, abits, rmax);
  gat_k3_pv<<<dim3(CC * (NN / 64)), dim3(256), 0, stream>>>(htT, esrc, edst, abits, rmax, out);
}